// Round 10
// baseline (40.811 us; speedup 1.0000x reference)
//
#include <hip/hip_runtime.h>

// SimpleUnsharedPatchScorer — register-run reduction, 128B-line coalesced lane map.
// t = i*9408 + j*588 + c*196 + h*14 + w  (i,j in [0,16), c in [0,3), h,w in [0,14))
// value at t: x[b, c, 16h+i, 16w+j];  out bin p = t/768.
// R9 post-mortem: 35.9us; run streams at ~5.2 TB/s. Old lane map (i*4+j4) made each
// wave-load touch 16x 64B segments. New map: lane = i2*8+q, 8-lane groups read 128B
// contiguous; q<4 lanes take even w, q>=4 odd w of the same (i,j) runs. wlay permuted
// to keep weight loads linear. LDS commits double to ~5.6M ds_add_f32 (still cheap).

#define NPATCH 196
#define NF4IMG 37632     // float4s per image = 150528/4
#define BSTR   197       // LDS bin row stride

// wlay layout (float4 index): (((tile*2 + ihalf)*7 + s)*64 + lane), lane = i2*8+q,
// element u holds weight at t(i=ihalf*8+i2, jj=4*(q&3)+u, c,h, w=2s+(q>>2)).
__global__ __launch_bounds__(256) void prep_kernel(
    const float* __restrict__ weight,
    const float* __restrict__ bias,
    float* __restrict__ wlay,
    float* __restrict__ out)
{
    const int bid = blockIdx.x;
    if (bid < 147) {                          // 147*256*4 == 150528 weights
        const int t4 = bid * 256 + threadIdx.x;
        const float4 wv = ((const float4*)weight)[t4];
        const float wt[4] = {wv.x, wv.y, wv.z, wv.w};
        #pragma unroll
        for (int u = 0; u < 4; ++u) {
            const int t    = 4 * t4 + u;
            const int i    = t / 9408;
            const int rem  = t - i * 9408;
            const int jj   = rem / 588;
            const int rem2 = rem - jj * 588;
            const int c    = rem2 / 196;
            const int rem3 = rem2 - c * 196;
            const int h    = rem3 / 14;
            const int w    = rem3 - h * 14;
            const int tile  = c * 14 + h;
            const int ihalf = i >> 3;
            const int i2    = i & 7;
            const int q     = (jj >> 2) + ((w & 1) << 2);
            const int s     = w >> 1;
            const int lane  = i2 * 8 + q;
            const int uu    = jj & 3;
            wlay[((((tile * 2 + ihalf) * 7 + s) * 64) + lane) * 4 + uu] = wt[u];
        }
    } else {                                  // 49*256*4 == 50176 == 256*196 bias-init
        const int g4 = (bid - 147) * 256 + threadIdx.x;
        const int g  = 4 * g4;
        float4 o;
        o.x = bias[(g + 0) % NPATCH];
        o.y = bias[(g + 1) % NPATCH];
        o.z = bias[(g + 2) % NPATCH];
        o.w = bias[(g + 3) % NPATCH];
        ((float4*)out)[g4] = o;
    }
}

__global__ __launch_bounds__(448) void run_kernel(
    const float* __restrict__ x,     // [256,3,224,224]
    const float* __restrict__ wlay,  // permuted weights (602112 floats)
    float* __restrict__ out)         // [256,196], bias pre-loaded
{
    __shared__ float bins[7 * BSTR];
    const int tid  = threadIdx.x;
    const int b    = blockIdx.x >> 1;         // image
    const int hh   = blockIdx.x & 1;          // h half
    const int wv   = tid >> 6;                // wave 0..6
    const int lane = tid & 63;
    const int i2   = lane >> 3;               // row within i-half
    const int q    = lane & 7;                // 8-lane 128B group
    const int q3   = q & 3;                   // j block
    const int wodd = q >> 2;                  // 0: even w, 1: odd w
    const int h    = hh * 7 + wv;

    for (int k = tid; k < 7 * BSTR; k += 448) bins[k] = 0.0f;
    __syncthreads();

    float* mybins = bins + wv * BSTR;

    #pragma unroll
    for (int c = 0; c < 3; ++c) {
        const int tile = c * 14 + h;
        #pragma unroll
        for (int ihalf = 0; ihalf < 2; ++ihalf) {
            const int i = ihalf * 8 + i2;
            const float4* __restrict__ x4 = (const float4*)x + (size_t)b * NF4IMG
                                            + c * 12544 + (16 * h + i) * 56 + q;
            const float4* __restrict__ w4 = (const float4*)wlay
                                            + (tile * 2 + ihalf) * 7 * 64 + lane;

            int p0[4], ws_[4];
            #pragma unroll
            for (int u = 0; u < 4; ++u) {
                const int jj = 4 * q3 + u;
                const int t0 = i * 9408 + jj * 588 + c * 196 + h * 14;
                p0[u]  = t0 / 768;
                ws_[u] = 768 * (p0[u] + 1) - t0;   // w >= ws_ -> bin p0+1 (ws_=14 => no split)
            }

            float accA[4] = {0.f, 0.f, 0.f, 0.f};
            float accB[4] = {0.f, 0.f, 0.f, 0.f};
            #pragma unroll
            for (int s = 0; s < 7; ++s) {
                const float4 xv  = x4[8 * s];      // 8 lanes x 16B = 128B line per group
                const float4 wv_ = w4[64 * s];     // wave reads 1KB linear
                const int w = 2 * s + wodd;
                const float xs[4]  = {xv.x, xv.y, xv.z, xv.w};
                const float wsv[4] = {wv_.x, wv_.y, wv_.z, wv_.w};
                #pragma unroll
                for (int u = 0; u < 4; ++u) {
                    const float v   = xs[u] * wsv[u];
                    const float sel = (w < ws_[u]) ? 1.0f : 0.0f;
                    accA[u] = fmaf(v, sel, accA[u]);
                    accB[u] = fmaf(v, 1.0f - sel, accB[u]);
                }
            }

            #pragma unroll
            for (int u = 0; u < 4; ++u) {
                unsafeAtomicAdd(&mybins[p0[u]], accA[u]);          // ds_add_f32
                if (ws_[u] < 14)
                    unsafeAtomicAdd(&mybins[p0[u] + 1], accB[u]);  // split tail (accB may be 0)
            }
        }
    }
    __syncthreads();

    // 7-way tree sum, then one device atomic per (block, p): 196*512 ~= 100K total
    for (int p = tid; p < NPATCH; p += 448) {
        float s = 0.0f;
        #pragma unroll
        for (int k = 0; k < 7; ++k) s += bins[k * BSTR + p];
        unsafeAtomicAdd(&out[b * NPATCH + p], s);
    }
}

extern "C" void kernel_launch(void* const* d_in, const int* in_sizes, int n_in,
                              void* d_out, int out_size, void* d_ws, size_t ws_size,
                              hipStream_t stream) {
    const float* x      = (const float*)d_in[0];
    const float* weight = (const float*)d_in[1];
    const float* bias   = (const float*)d_in[2];
    float* out          = (float*)d_out;
    float* wlay         = (float*)d_ws;      // 602112 bytes

    prep_kernel<<<196, 256, 0, stream>>>(weight, bias, wlay, out);
    run_kernel<<<512, 448, 0, stream>>>(x, wlay, out);
}

// Round 11
// 36.291 us; speedup vs baseline: 1.1245x; 1.1245x over previous
//
#include <hip/hip_runtime.h>

// SimpleUnsharedPatchScorer — register-run reduction, 128B lane map + shfl pair-combine.
// t = i*9408 + j*588 + c*196 + h*14 + w  (i,j in [0,16), c in [0,3), h,w in [0,14))
// value at t: x[b, c, 16h+i, 16w+j];  out bin p = t/768.
// R10 post-mortem: 128B map regressed (40.8) because commits doubled AND became pairwise
// same-address (even/odd-w lanes share bins) -> ~4x LDS-atomic cost. Confounded A/B.
// R11: keep 128B map; fold partner lanes with __shfl_xor(acc,4) so only wodd==0 lanes
// commit -> 2.75M conflict-free ds_add_f32 (same as R9). Clean test of coalescing gain.

#define NPATCH 196
#define NF4IMG 37632     // float4s per image = 150528/4
#define BSTR   197       // LDS bin row stride

// wlay layout (float4 index): ((tile*2 + ihalf)*7 + s)*64 + lane, lane = i2*8+q,
// element u holds weight at t(i=ihalf*8+i2, jj=4*(q&3)+u, c,h, w=2s+(q>>2)).
__global__ __launch_bounds__(256) void prep_kernel(
    const float* __restrict__ weight,
    const float* __restrict__ bias,
    float* __restrict__ wlay,
    float* __restrict__ out)
{
    const int bid = blockIdx.x;
    if (bid < 147) {                          // 147*256*4 == 150528 weights
        const int t4 = bid * 256 + threadIdx.x;
        const float4 wv = ((const float4*)weight)[t4];
        const float wt[4] = {wv.x, wv.y, wv.z, wv.w};
        #pragma unroll
        for (int u = 0; u < 4; ++u) {
            const int t    = 4 * t4 + u;
            const int i    = t / 9408;
            const int rem  = t - i * 9408;
            const int jj   = rem / 588;
            const int rem2 = rem - jj * 588;
            const int c    = rem2 / 196;
            const int rem3 = rem2 - c * 196;
            const int h    = rem3 / 14;
            const int w    = rem3 - h * 14;
            const int tile  = c * 14 + h;
            const int ihalf = i >> 3;
            const int i2    = i & 7;
            const int q     = (jj >> 2) + ((w & 1) << 2);
            const int s     = w >> 1;
            const int lane  = i2 * 8 + q;
            const int uu    = jj & 3;
            wlay[((((tile * 2 + ihalf) * 7 + s) * 64) + lane) * 4 + uu] = wt[u];
        }
    } else {                                  // 49*256*4 == 50176 == 256*196 bias-init
        const int g4 = (bid - 147) * 256 + threadIdx.x;
        const int g  = 4 * g4;
        float4 o;
        o.x = bias[(g + 0) % NPATCH];
        o.y = bias[(g + 1) % NPATCH];
        o.z = bias[(g + 2) % NPATCH];
        o.w = bias[(g + 3) % NPATCH];
        ((float4*)out)[g4] = o;
    }
}

__global__ __launch_bounds__(448) void run_kernel(
    const float* __restrict__ x,     // [256,3,224,224]
    const float* __restrict__ wlay,  // permuted weights (602112 floats)
    float* __restrict__ out)         // [256,196], bias pre-loaded
{
    __shared__ float bins[7 * BSTR];
    const int tid  = threadIdx.x;
    const int b    = blockIdx.x >> 1;         // image
    const int hh   = blockIdx.x & 1;          // h half
    const int wv   = tid >> 6;                // wave 0..6
    const int lane = tid & 63;
    const int i2   = lane >> 3;               // row within i-half
    const int q    = lane & 7;                // 8-lane 128B group
    const int q3   = q & 3;                   // j block
    const int wodd = q >> 2;                  // 0: even w, 1: odd w
    const int h    = hh * 7 + wv;

    for (int k = tid; k < 7 * BSTR; k += 448) bins[k] = 0.0f;
    __syncthreads();

    float* mybins = bins + wv * BSTR;

    #pragma unroll
    for (int c = 0; c < 3; ++c) {
        const int tile = c * 14 + h;
        #pragma unroll
        for (int ihalf = 0; ihalf < 2; ++ihalf) {
            const int i = ihalf * 8 + i2;
            const float4* __restrict__ x4 = (const float4*)x + (size_t)b * NF4IMG
                                            + c * 12544 + (16 * h + i) * 56 + q;
            const float4* __restrict__ w4 = (const float4*)wlay
                                            + (tile * 2 + ihalf) * 7 * 64 + lane;

            int p0[4], ws_[4];
            #pragma unroll
            for (int u = 0; u < 4; ++u) {
                const int jj = 4 * q3 + u;
                const int t0 = i * 9408 + jj * 588 + c * 196 + h * 14;
                p0[u]  = t0 / 768;
                ws_[u] = 768 * (p0[u] + 1) - t0;   // w >= ws_ -> bin p0+1 (ws_=14 => no split)
            }

            float accA[4] = {0.f, 0.f, 0.f, 0.f};
            float accB[4] = {0.f, 0.f, 0.f, 0.f};
            #pragma unroll
            for (int s = 0; s < 7; ++s) {
                const float4 xv  = x4[8 * s];      // 8 lanes x 16B = full 128B line
                const float4 wv_ = w4[64 * s];     // wave reads 1KB linear
                const int w = 2 * s + wodd;
                const float xs[4]  = {xv.x, xv.y, xv.z, xv.w};
                const float wsv[4] = {wv_.x, wv_.y, wv_.z, wv_.w};
                #pragma unroll
                for (int u = 0; u < 4; ++u) {
                    const float v   = xs[u] * wsv[u];
                    const float sel = (w < ws_[u]) ? 1.0f : 0.0f;
                    accA[u] = fmaf(v, sel, accA[u]);
                    accB[u] = fmaf(v, 1.0f - sel, accB[u]);
                }
            }

            // fold even/odd-w partner (lane ^ 4): same (i,jj) runs -> same bins
            #pragma unroll
            for (int u = 0; u < 4; ++u) {
                accA[u] += __shfl_xor(accA[u], 4, 64);
                accB[u] += __shfl_xor(accB[u], 4, 64);
            }
            if (wodd == 0) {                       // half-wave commits; count == R9 level
                #pragma unroll
                for (int u = 0; u < 4; ++u) {
                    unsafeAtomicAdd(&mybins[p0[u]], accA[u]);          // ds_add_f32
                    if (ws_[u] < 14)
                        unsafeAtomicAdd(&mybins[p0[u] + 1], accB[u]);  // rare split
                }
            }
        }
    }
    __syncthreads();

    // 7-way tree sum, then one device atomic per (block, p): 196*512 ~= 100K total
    for (int p = tid; p < NPATCH; p += 448) {
        float s = 0.0f;
        #pragma unroll
        for (int k = 0; k < 7; ++k) s += bins[k * BSTR + p];
        unsafeAtomicAdd(&out[b * NPATCH + p], s);
    }
}

extern "C" void kernel_launch(void* const* d_in, const int* in_sizes, int n_in,
                              void* d_out, int out_size, void* d_ws, size_t ws_size,
                              hipStream_t stream) {
    const float* x      = (const float*)d_in[0];
    const float* weight = (const float*)d_in[1];
    const float* bias   = (const float*)d_in[2];
    float* out          = (float*)d_out;
    float* wlay         = (float*)d_ws;      // 602112 bytes

    prep_kernel<<<196, 256, 0, stream>>>(weight, bias, wlay, out);
    run_kernel<<<512, 448, 0, stream>>>(x, wlay, out);
}